// Round 9
// baseline (447.270 us; speedup 1.0000x reference)
//
#include <hip/hip_runtime.h>
#include <hip/hip_bf16.h>
#include <math.h>

#define DIM   512
#define HIDW  256
#define ATTW  128
#define MAXC  50
#define BLK   256
#define KW    128    // kb (corr/K2) stride, swizzled
#define HLW   128    // hl stride, swizzled
#define HL2   264    // fallback hidden stride
#define BUFW  136    // fallback stride
#define SB_W  52
#define CH    10
#define PXR   32     // proj row-tile
#define SCL   0.08838834764831845f  // 1/sqrt(128)

// 16B-block-preserving XOR swizzle (T2)
#define SWZ(row, e) ((e) ^ (((row) & 7) << 3))

// attn LDS layout (32000 B -> 5 blocks/CU):
#define AT_PA 12800
#define AT_KB 19200
#define AT_SM 32000

typedef float f32x4 __attribute__((ext_vector_type(4)));
typedef short s16x8 __attribute__((ext_vector_type(8)));

__device__ __forceinline__ float bf2f(ushort u){ union{unsigned i;float f;}v; v.i=((unsigned)u)<<16; return v.f; }
__device__ __forceinline__ ushort f2bf(float f){
  union{float f;unsigned i;}v; v.f=f;
  unsigned r = v.i + 0x7fffu + ((v.i>>16)&1u);
  return (ushort)(r>>16);
}
__device__ __forceinline__ s16x8 ldfrag(const ushort* p){ s16x8 v; __builtin_memcpy(&v, p, 16); return v; }
__device__ __forceinline__ f32x4 mfma16(s16x8 a, s16x8 b, f32x4 c){
  return __builtin_amdgcn_mfma_f32_16x16x32_bf16(a, b, c, 0, 0, 0);
}
// fragment-ordered weight pointer: tile (ntile,ktile) of an (N x K) matrix, lane L
__device__ __forceinline__ const ushort* fragp(const ushort* Wf, int ntile, int ktile, int KT, int L){
  return Wf + (((size_t)ntile*KT + ktile)*64 + L)*8;
}

template<bool F32>
__device__ __forceinline__ float ld(const void* p, int i){
  if (F32) return ((const float*)p)[i];
  return bf2f(((const ushort*)p)[i]);
}

struct P27 {
  const void *molA, *nodeH; const int* counts;
  const void *wq1,*bq1,*wq2,*bq2, *wk1,*bk1,*wk2,*bk2, *wv1,*bv1,*wv2,*bv2;
  const void *uk1,*ubk1,*uk2,*ubk2, *uq1,*ubq1,*uq2,*ubq2;
  const void *cs1,*bcs1,*cs2,*bcs2;
  void* out;
};

// workspace: wsInt[0]=f32flag, wsInt[4..4+nb) offsets; wt (bf16, FRAGMENT layout) at 8704
#define O_WK1T 0
#define O_WQ1T 131072
#define O_WV1T 262144
#define O_WK2T 393216
#define O_WQ2T 425984
#define O_WV2T 458752
#define O_UK1T 491520
#define O_UK2T 524288
#define WT_ELEMS   557056
#define O_UQ1TT 557056
#define O_UQ2TT 688128
#define WT2_ELEMS  720896
#define WT_T2ELEMS 393216
#define WT_BYTE_OFF 8704
#define Q2_BYTE_OFF (WT_BYTE_OFF + WT2_ELEMS*2)   // 1450496, 16B-aligned

// ---------- dtype self-detect (block-local, molA exponent histogram) ----------
__device__ __forceinline__ int detect_f32m(const ushort* molAu, int t, int* cntSh)
{
  if (t == 0) *cntSh = 0;
  __syncthreads();
  int e = (molAu[t] >> 7) & 0xFF;
  if (e >= 100 && e <= 140) atomicAdd(cntSh, 1);
  __syncthreads();
  return (*cntSh >= 220) ? 0 : 1;
}

// ---------- prep: dtype detect + exclusive scan (standalone, scalar tier) ----------
__global__ void prep_kernel(const ushort* __restrict__ molAu,
                            const int* __restrict__ counts, int nb,
                            int* __restrict__ wsInt)
{
  __shared__ int part[BLK];
  __shared__ int cnt;
  const int t = threadIdx.x;
  if (t == 0) cnt = 0;
  __syncthreads();
  int e = (molAu[t] >> 7) & 0xFF;
  if (e >= 100 && e <= 140) atomicAdd(&cnt, 1);
  const int per = (nb + BLK - 1) / BLK;
  int s = 0;
  for (int i = 0; i < per; i++) { int idx = t*per + i; if (idx < nb) s += counts[idx]; }
  part[t] = s;
  __syncthreads();
  if (t == 0) {
    int run = 0;
    for (int i = 0; i < BLK; i++) { int v = part[i]; part[i] = run; run += v; }
    wsInt[0] = (cnt >= 220) ? 0 : 1;        // 0 = bf16 inputs, 1 = f32 inputs
  }
  __syncthreads();
  int run = part[t];
  for (int i = 0; i < per; i++) {
    int idx = t*per + i;
    if (idx < nb) { wsInt[4 + idx] = run; run += counts[idx]; }
  }
}

// ---------- merged prep2: weight transpose (self-detect) + prep block ----------
__global__ void prep2_kernel(P27 P, const int* __restrict__ counts, int nb,
                             int* __restrict__ wsInt,
                             ushort* __restrict__ wt, unsigned long long cap_elems,
                             unsigned nwt)
{
  __shared__ int shInt[BLK];
  const int t = threadIdx.x;
  const unsigned bid = blockIdx.x;

  if (bid == nwt) {
    // ---- prep block: dtype detect + exclusive scan ----
    __shared__ int cnt;
    if (t == 0) cnt = 0;
    __syncthreads();
    int e = (((const ushort*)P.molA)[t] >> 7) & 0xFF;
    if (e >= 100 && e <= 140) atomicAdd(&cnt, 1);
    const int per = (nb + BLK - 1) / BLK;
    int s = 0;
    for (int i = 0; i < per; i++) { int idx = t*per + i; if (idx < nb) s += counts[idx]; }
    shInt[t] = s;
    __syncthreads();
    if (t == 0) {
      int run = 0;
      for (int i = 0; i < BLK; i++) { int v = shInt[i]; shInt[i] = run; run += v; }
      wsInt[0] = (cnt >= 220) ? 0 : 1;
    }
    __syncthreads();
    int run = shInt[t];
    for (int i = 0; i < per; i++) {
      int idx = t*per + i;
      if (idx < nb) { wsInt[4 + idx] = run; run += counts[idx]; }
    }
    return;
  }

  // ---- transpose block: self-detect dtype, then fragment-layout convert ----
  const int f32m = detect_f32m((const ushort*)P.molA, t, &shInt[0]);
  unsigned i = bid*BLK + t;
  if (i >= WT2_ELEMS) return;
  if ((unsigned long long)i >= cap_elems) return;
  const void* src; unsigned j; int K, ldw;
  if (i < O_WK2T) {                 // w1-type: N=256, K=512, src[k*256+n]
    int m = i / 131072; j = i - m*131072;
    src = (m==0) ? P.wk1 : ((m==1) ? P.wq1 : P.wv1);
    K = 512; ldw = HIDW;
  } else if (i < O_UK1T) {          // w2-type: N=128, K=256, src[k*128+n]
    int m = (i - O_WK2T) / 32768; j = (i - O_WK2T) - m*32768;
    src = (m==0) ? P.wk2 : ((m==1) ? P.wq2 : P.wv2);
    K = 256; ldw = ATTW;
  } else if (i < O_UK2T) {          // uk1: N=256, K=128
    j = i - O_UK1T; src = P.uk1;  K = 128; ldw = HIDW;
  } else if (i < O_UQ1TT) {         // uk2: N=128, K=256
    j = i - O_UK2T; src = P.uk2;  K = 256; ldw = ATTW;
  } else if (i < O_UQ2TT) {         // uq1: N=256, K=512
    j = i - O_UQ1TT; src = P.uq1; K = 512; ldw = HIDW;
  } else {                          // uq2: N=128, K=256
    j = i - O_UQ2TT; src = P.uq2; K = 256; ldw = ATTW;
  }
  int tile = j >> 9, within = j & 511;
  int Lp = within >> 3, jj = within & 7;
  int l16 = Lp & 15, quad = Lp >> 4;
  int KT = K >> 5;
  int ntile = tile / KT, ktile = tile - ntile*KT;
  int n = ntile*16 + l16;
  int k = ktile*32 + quad*8 + jj;
  int idx = k*ldw + n;
  float v = f32m ? ((const float*)src)[idx] : bf2f(((const ushort*)src)[idx]);
  wt[i] = f2bf(v);
}

// ================= fused projection GEMM (r4-exact, measured 157.9 µs) =================
// nodeH blocks: sets K,Q,V -> kqv planes. molA blocks: set Q2 -> q2ws (f32).
__global__ void __launch_bounds__(BLK, 3)
proj_kernel(P27 P, const int* __restrict__ wsInt, const ushort* __restrict__ wt,
            ushort* __restrict__ kqv, float* __restrict__ q2ws,
            long Nrows, int nb, int ntX)
{
  __shared__ __align__(16) ushort xs [PXR*DIM];    // 32768 B, swizzled
  __shared__ __align__(16) ushort hid[PXR*HIDW];   // 16384 B, swizzled
  const int t = threadIdx.x, bid = blockIdx.x;
  const int f32m = wsInt[0];
  const long NP = Nrows * ATTW;
  const bool isml = (bid >= ntX);
  const long r0 = isml ? (long)(bid - ntX)*PXR : (long)bid*PXR;
  int rows;
  const void* X;
  if (isml) { int rem = nb - (int)r0;        rows = (rem < PXR) ? rem : PXR; X = P.molA; }
  else      { long rem = Nrows - r0;         rows = (rem < PXR) ? (int)rem : PXR; X = P.nodeH; }
  if (rows <= 0) return;

  // ---- stage X-tile -> xs (bf16, swizzled; conversion paid once) ----
  for (int i = t*8; i < PXR*DIM; i += BLK*8) {
    int row = i >> 9;
    int e   = i & (DIM-1);
    s16x8 o = {};
    if (row < rows) {
      if (f32m) {
        const float* xp = (const float*)X + (r0 + row)*DIM + e;
        f32x4 v0, v1; __builtin_memcpy(&v0, xp, 16); __builtin_memcpy(&v1, xp+4, 16);
#pragma unroll
        for (int q = 0; q < 4; q++) { o[q] = (short)f2bf(v0[q]); o[4+q] = (short)f2bf(v1[q]); }
      } else {
        o = ldfrag((const ushort*)X + (r0 + row)*DIM + e);
      }
    }
    __builtin_memcpy(&xs[row*DIM + SWZ(row, e)], &o, 16);
  }
  __syncthreads();

  const int w = t >> 6, L = t & 63, quad = L >> 4, l16 = L & 15;
  const int nsets = isml ? 1 : 3;
  for (int si = 0; si < nsets; si++) {
    const ushort *W1t, *W2t; const void *b1, *b2;
    if (isml)        { W1t = wt+O_UQ1TT; b1 = P.ubq1; W2t = wt+O_UQ2TT; b2 = P.ubq2; }
    else if (si==0)  { W1t = wt+O_WK1T;  b1 = P.bk1;  W2t = wt+O_WK2T;  b2 = P.bk2;  }
    else if (si==1)  { W1t = wt+O_WQ1T;  b1 = P.bq1;  W2t = wt+O_WQ2T;  b2 = P.bq2;  }
    else             { W1t = wt+O_WV1T;  b1 = P.bv1;  W2t = wt+O_WV2T;  b2 = P.bv2;  }

    // ---- layer1: xs(32x512) @ W1t -> acc; wave w owns cols [w*64, w*64+64) ----
    f32x4 acc[2][4];
#pragma unroll
    for (int i = 0; i < 2; i++)
#pragma unroll
      for (int jn = 0; jn < 4; jn++) acc[i][jn] = (f32x4){0.f,0.f,0.f,0.f};
#pragma unroll 2
    for (int k0 = 0; k0 < DIM; k0 += 32) {
      const int kt = k0 >> 5;
      const int eo = SWZ(l16, k0 + quad*8);
      s16x8 a0 = ldfrag(xs + l16*DIM + eo);
      s16x8 a1 = ldfrag(xs + (16 + l16)*DIM + eo);
#pragma unroll
      for (int nt = 0; nt < 4; nt++) {
        s16x8 b = ldfrag(fragp(W1t, w*4 + nt, kt, 16, L));
        acc[0][nt] = mfma16(a0, b, acc[0][nt]);
        acc[1][nt] = mfma16(a1, b, acc[1][nt]);
      }
    }
    __syncthreads();   // prior set's layer2 hid reads complete
#pragma unroll
    for (int nt = 0; nt < 4; nt++) {
      int col = w*64 + nt*16 + l16;
      float bb = f32m ? ((const float*)b1)[col] : bf2f(((const ushort*)b1)[col]);
#pragma unroll
      for (int mt = 0; mt < 2; mt++)
#pragma unroll
        for (int r = 0; r < 4; r++) {
          int row = mt*16 + quad*4 + r;
          hid[row*HIDW + SWZ(row, col)] = f2bf(fmaxf(acc[mt][nt][r] + bb, 0.f));
        }
    }
    __syncthreads();

    // ---- layer2: hid(32x256) @ W2t -> out; wave w owns cols [w*32, w*32+32) ----
    f32x4 acc2[2][2];
#pragma unroll
    for (int i = 0; i < 2; i++) { acc2[i][0] = (f32x4){0.f,0.f,0.f,0.f}; acc2[i][1] = (f32x4){0.f,0.f,0.f,0.f}; }
#pragma unroll 2
    for (int k0 = 0; k0 < HIDW; k0 += 32) {
      const int kt = k0 >> 5;
      const int eo = SWZ(l16, k0 + quad*8);
      s16x8 a0 = ldfrag(hid + l16*HIDW + eo);
      s16x8 a1 = ldfrag(hid + (16 + l16)*HIDW + eo);
      s16x8 b0 = ldfrag(fragp(W2t, w*2,     kt, 8, L));
      s16x8 b1v= ldfrag(fragp(W2t, w*2 + 1, kt, 8, L));
      acc2[0][0] = mfma16(a0, b0,  acc2[0][0]);
      acc2[0][1] = mfma16(a0, b1v, acc2[0][1]);
      acc2[1][0] = mfma16(a1, b0,  acc2[1][0]);
      acc2[1][1] = mfma16(a1, b1v, acc2[1][1]);
    }
#pragma unroll
    for (int nt = 0; nt < 2; nt++) {
      int col = w*32 + nt*16 + l16;
      float bb = f32m ? ((const float*)b2)[col] : bf2f(((const ushort*)b2)[col]);
#pragma unroll
      for (int mt = 0; mt < 2; mt++)
#pragma unroll
        for (int r = 0; r < 4; r++) {
          int row = mt*16 + quad*4 + r;
          if (row < rows) {
            float v = acc2[mt][nt][r] + bb;
            if (isml) q2ws[(r0 + row)*ATTW + col] = v;
            else      kqv[(size_t)si*NP + (r0 + row)*ATTW + col] = f2bf(v);
          }
        }
    }
  }
}

// ================= per-molecule attention kernel =================

__device__ __forceinline__ void scores_g(const ushort* __restrict__ Kp,
                                         const ushort* __restrict__ Qp,
                                         long offset, int c,
                                         float* __restrict__ sb, int t)
{
  const int w = t >> 6, L = t & 63, quad = L >> 4, l16 = L & 15;
  f32x4 acc[4];
#pragma unroll
  for (int i = 0; i < 4; i++) acc[i] = (f32x4){0.f,0.f,0.f,0.f};
  const int col = w*16 + l16;
  const long gq = offset + ((col < c) ? col : 0);
  long ga[4];
#pragma unroll
  for (int mt = 0; mt < 4; mt++) {
    int row = mt*16 + l16;
    ga[mt] = offset + ((row < c) ? row : 0);
  }
#pragma unroll
  for (int k0 = 0; k0 < ATTW; k0 += 32) {
    s16x8 b = ldfrag(Qp + (size_t)gq*ATTW + k0 + quad*8);
#pragma unroll
    for (int mt = 0; mt < 4; mt++) {
      s16x8 a = ldfrag(Kp + (size_t)ga[mt]*ATTW + k0 + quad*8);
      acc[mt] = mfma16(a, b, acc[mt]);
    }
  }
#pragma unroll
  for (int mt = 0; mt < 4; mt++)
#pragma unroll
    for (int r = 0; r < 4; r++) {
      int row = mt*16 + quad*4 + r;
      if (row < MAXC && col < MAXC)
        sb[row*SB_W + col] = (row < c && col < c) ? acc[mt][r]*SCL : -1e9f*SCL;
    }
}

__device__ __forceinline__ void softmax_pa(float* __restrict__ sb,
                                           ushort* __restrict__ pa, int c, int t)
{
  const int m = t >> 2, j = t & 3;
  if (m < MAXC) {
    float* row = sb + m*SB_W;
    float mx = -3.4e38f;
    for (int n = j; n < MAXC; n += 4) mx = fmaxf(mx, row[n]);
    mx = fmaxf(mx, __shfl_xor(mx, 1));
    mx = fmaxf(mx, __shfl_xor(mx, 2));
    float sum = 0.f;
    for (int n = j; n < MAXC; n += 4) { float e = expf(row[n] - mx); row[n] = e; sum += e; }
    sum += __shfl_xor(sum, 1);
    sum += __shfl_xor(sum, 2);
    float inv = 1.f / sum;
    for (int n = j; n < 64; n += 4)
      pa[m*64 + SWZ(m, n)] = (n < MAXC) ? f2bf(row[n] * inv) : (ushort)0;
  }
}

__device__ __forceinline__ void corr_half(const ushort* __restrict__ pa,
                                          const ushort* __restrict__ vt,
                                          ushort* __restrict__ dst, int colbase, int t)
{
  const int w = t >> 6, L = t & 63, quad = L >> 4, l16 = L & 15;
  f32x4 acc[4];
#pragma unroll
  for (int i = 0; i < 4; i++) acc[i] = (f32x4){0.f,0.f,0.f,0.f};
  const int dr = w*16 + l16;
#pragma unroll
  for (int k0 = 0; k0 < 64; k0 += 32) {
    s16x8 b = ldfrag(vt + dr*64 + SWZ(dr, k0 + quad*8));
#pragma unroll
    for (int mt = 0; mt < 4; mt++) {
      int row = mt*16 + l16;
      int ar = (row < MAXC) ? row : 0;
      s16x8 a = ldfrag(pa + ar*64 + SWZ(ar, k0 + quad*8));
      acc[mt] = mfma16(a, b, acc[mt]);
    }
  }
  const int col = colbase + w*16 + l16;
#pragma unroll
  for (int mt = 0; mt < 4; mt++)
#pragma unroll
    for (int r = 0; r < 4; r++) {
      int row = mt*16 + quad*4 + r;
      if (row < MAXC)
        dst[row*KW + SWZ(row, col)] = f2bf(acc[mt][r]);
    }
}

// K2-stage1 half (uk1: N=256,K=128 frag layout)
template<bool F32>
__device__ __forceinline__ void s1l_half(const ushort* __restrict__ src,
                                         const ushort* __restrict__ W1t,
                                         const void* __restrict__ Bv,
                                         ushort* __restrict__ hl, int t, int h)
{
  const int w = t >> 6, L = t & 63, quad = L >> 4, l16 = L & 15;
  f32x4 acc[4][2];
#pragma unroll
  for (int i = 0; i < 4; i++) { acc[i][0] = (f32x4){0.f,0.f,0.f,0.f}; acc[i][1] = (f32x4){0.f,0.f,0.f,0.f}; }
#pragma unroll
  for (int k0 = 0; k0 < ATTW; k0 += 32) {
    const int kt = k0 >> 5;
    s16x8 b0 = ldfrag(fragp(W1t, h*8 + w*2,     kt, 4, L));
    s16x8 b1 = ldfrag(fragp(W1t, h*8 + w*2 + 1, kt, 4, L));
#pragma unroll
    for (int mt = 0; mt < 4; mt++) {
      int row = mt*16 + l16;
      int ar = (row < MAXC) ? row : 0;
      s16x8 a = ldfrag(src + ar*KW + SWZ(ar, k0 + quad*8));
      acc[mt][0] = mfma16(a, b0, acc[mt][0]);
      acc[mt][1] = mfma16(a, b1, acc[mt][1]);
    }
  }
#pragma unroll
  for (int nt = 0; nt < 2; nt++) {
    int lcol = w*32 + nt*16 + l16;
    float bb = ld<F32>(Bv, h*128 + lcol);
#pragma unroll
    for (int mt = 0; mt < 4; mt++)
#pragma unroll
      for (int r = 0; r < 4; r++) {
        int row = mt*16 + quad*4 + r;
        if (row < MAXC)
          hl[row*HLW + SWZ(row, lcol)] = f2bf(fmaxf(acc[mt][nt][r] + bb, 0.f));
      }
  }
}

// K2-stage2 partial (uk2: N=128,K=256 frag layout), hidden half h
template<bool F32>
__device__ __forceinline__ void s2_partial(const ushort* __restrict__ hl,
                                           const ushort* __restrict__ W2t,
                                           int h, f32x4 (&acc)[4][2], int t)
{
  const int w = t >> 6, L = t & 63, quad = L >> 4, l16 = L & 15;
#pragma unroll
  for (int k0 = 0; k0 < 128; k0 += 32) {
    const int kt = h*4 + (k0 >> 5);
    s16x8 b0 = ldfrag(fragp(W2t, w*2,     kt, 8, L));
    s16x8 b1 = ldfrag(fragp(W2t, w*2 + 1, kt, 8, L));
#pragma unroll
    for (int mt = 0; mt < 4; mt++) {
      int row = mt*16 + l16;
      int ar = (row < MAXC) ? row : 0;
      s16x8 a = ldfrag(hl + ar*HLW + SWZ(ar, k0 + quad*8));
      acc[mt][0] = mfma16(a, b0, acc[mt][0]);
      acc[mt][1] = mfma16(a, b1, acc[mt][1]);
    }
  }
}

template<bool F32>
__device__ __forceinline__ void s2_store(f32x4 (&acc)[4][2], const void* __restrict__ Bv,
                                         ushort* __restrict__ dst, int t)
{
  const int w = t >> 6, L = t & 63, quad = L >> 4, l16 = L & 15;
#pragma unroll
  for (int nt = 0; nt < 2; nt++) {
    int col = w*32 + nt*16 + l16;
    float bb = ld<F32>(Bv, col);
#pragma unroll
    for (int mt = 0; mt < 4; mt++)
#pragma unroll
      for (int r = 0; r < 4; r++) {
        int row = mt*16 + quad*4 + r;
        if (row < MAXC)
          dst[row*KW + SWZ(row, col)] = f2bf(acc[mt][nt][r] + bb);
      }
  }
}

template<bool F32>
__device__ void attn_body(const P27& P, int b, int t, char* smem,
                          long offset, int c,
                          const ushort* __restrict__ wt,
                          const ushort* __restrict__ Kp, const ushort* __restrict__ Qp,
                          const ushort* __restrict__ Vp, const float* __restrict__ q2ws)
{
  float*  sb = (float*)smem;
  ushort* vt = (ushort*)smem;
  ushort* hl = (ushort*)smem;
  ushort* pa = (ushort*)(smem + AT_PA);
  ushort* kb = (ushort*)(smem + AT_KB);
  // tail scalars live in the pa region (pa dead after corr)
  float* q2   = (float*)(smem + AT_PA);          // 512 B
  float* lgt  = (float*)(smem + AT_PA + 512);    // 256 B
  float* selh = (float*)(smem + AT_PA + 768);    // 512 B

  scores_g(Kp, Qp, offset, c, sb, t);
  __syncthreads();
  softmax_pa(sb, pa, c, t);
  __syncthreads();

#pragma unroll
  for (int half = 0; half < 2; half++) {
    for (int i = t; i < 512; i += BLK) {
      int atom = i & 63, chunk = i >> 6;
      s16x8 f = {};
      if (atom < c) f = ldfrag(Vp + (size_t)(offset + atom)*ATTW + half*64 + chunk*8);
#pragma unroll
      for (int j = 0; j < 8; j++) {
        int d = chunk*8 + j;
        vt[d*64 + SWZ(d, atom)] = (ushort)f[j];
      }
    }
    __syncthreads();
    corr_half(pa, vt, kb, half*64, t);
    __syncthreads();
  }

  // q2 prefetch into dead pa region (visibility covered by K2's final barrier)
  if (t < ATTW) q2[t] = q2ws[(size_t)b*ATTW + t];

  {
    f32x4 acc[4][2];
#pragma unroll
    for (int i = 0; i < 4; i++) { acc[i][0] = (f32x4){0.f,0.f,0.f,0.f}; acc[i][1] = (f32x4){0.f,0.f,0.f,0.f}; }
    s1l_half<F32>(kb, wt + O_UK1T, P.ubk1, hl, t, 0); __syncthreads();
    s2_partial<F32>(hl, wt + O_UK2T, 0, acc, t);      __syncthreads();
    s1l_half<F32>(kb, wt + O_UK1T, P.ubk1, hl, t, 1); __syncthreads();
    s2_partial<F32>(hl, wt + O_UK2T, 1, acc, t);
    s2_store<F32>(acc, P.ubk2, kb, t);
    __syncthreads();
  }

  // ---- barrier-free tail: wave 0 only, wave-synchronous LDS ----
  if (t < 64) {
    if (t < MAXC) {
      float s = 0.f;
      for (int k = 0; k < ATTW; k++)
        s += bf2f(kb[t*KW + SWZ(t, k)]) * q2[k];
      lgt[t] = s * SCL;
    }
    for (int cc = t; cc < ATTW; cc += 64) {
      float a = 0.f;
      for (int k = 0; k < MAXC; k++)
        a += lgt[k] * ld<F32>(P.cs1, k*ATTW + cc);
      selh[cc] = fmaxf(a + ld<F32>(P.bcs1, cc), 0.f);
    }
    if (t < c) {
      float a = 0.f;
      for (int k = 0; k < ATTW; k++)
        a += selh[k] * ld<F32>(P.cs2, k*MAXC + t);
      a += ld<F32>(P.bcs2, t);
      float v = 1.f / (1.f + expf(-a));
      if (F32) ((float*)P.out)[offset + t] = v;
      else     ((ushort*)P.out)[offset + t] = f2bf(v);
    }
  }
}

__global__ void __launch_bounds__(BLK, 5)
attn_kernel(P27 P, const int* __restrict__ wsInt, const ushort* __restrict__ wt,
            const ushort* __restrict__ kqv, const float* __restrict__ q2ws, long Nrows)
{
  __shared__ __align__(16) char smem[AT_SM];
  const int t = threadIdx.x, b = blockIdx.x;
  const int f32m = wsInt[0];
  const long offset = wsInt[4 + b];
  const int c = P.counts[b];
  const long NP = Nrows * ATTW;
  const ushort* Kp = kqv;
  const ushort* Qp = kqv + NP;
  const ushort* Vp = kqv + 2*NP;
  if (f32m) attn_body<true >(P, b, t, smem, offset, c, wt, Kp, Qp, Vp, q2ws);
  else      attn_body<false>(P, b, t, smem, offset, c, wt, Kp, Qp, Vp, q2ws);
}

// ================= fallback tiers =================
template<bool F32, bool XB>
__device__ __forceinline__ void stage1_mfma(const void* __restrict__ X, int xb, int c,
                                            const ushort* __restrict__ Wt,
                                            const void* __restrict__ Bv,
                                            ushort* __restrict__ hl, int hls, int t,
                                            int wlim)
{
  const int w = t >> 6, L = t & 63, quad = L >> 4, l16 = L & 15;
  f32x4 acc[4][4];
#pragma unroll
  for (int i = 0; i < 4; i++)
#pragma unroll
    for (int j = 0; j < 4; j++) acc[i][j] = (f32x4){0.f,0.f,0.f,0.f};

  bool va[4]; int rr[4];
#pragma unroll
  for (int mt = 0; mt < 4; mt++) {
    int row = mt*16 + l16;
    va[mt] = (row < c);
    rr[mt] = va[mt] ? row : 0;
  }

#pragma unroll 2
  for (int k0 = 0; k0 < DIM; k0 += 32) {
    const int kt = k0 >> 5;
    s16x8 a[4];
#pragma unroll
    for (int mt = 0; mt < 4; mt++) {
      s16x8 z = {};
      if (va[mt]) {
        if (XB || !F32) {
          a[mt] = ldfrag((const ushort*)X + xb + rr[mt]*DIM + k0 + quad*8);
        } else {
          const float* xp = (const float*)X + xb + rr[mt]*DIM + k0 + quad*8;
          f32x4 v0, v1;
          __builtin_memcpy(&v0, xp, 16);
          __builtin_memcpy(&v1, xp+4, 16);
          s16x8 v;
#pragma unroll
          for (int j = 0; j < 4; j++) { v[j] = (short)f2bf(v0[j]); v[4+j] = (short)f2bf(v1[j]); }
          a[mt] = v;
        }
      } else a[mt] = z;
    }
#pragma unroll
    for (int nt = 0; nt < 4; nt++) {
      s16x8 b = ldfrag(fragp(Wt, w*4 + nt, kt, 16, L));
#pragma unroll
      for (int mt = 0; mt < 4; mt++)
        acc[mt][nt] = mfma16(a[mt], b, acc[mt][nt]);
    }
  }
#pragma unroll
  for (int nt = 0; nt < 4; nt++) {
    int col = w*64 + nt*16 + l16;
    float bb = ld<F32>(Bv, col);
#pragma unroll
    for (int mt = 0; mt < 4; mt++)
#pragma unroll
      for (int r = 0; r < 4; r++) {
        int row = mt*16 + quad*4 + r;
        if (row < wlim)
          hl[row*hls + col] = f2bf(fmaxf(acc[mt][nt][r] + bb, 0.f));
      }
  }
}

template<bool F32>
__device__ void stage1_g(const void* X, int xb, int c,
                         const void* W, const void* Bv, ushort* hl, int t)
{
  for (int r0 = 0; r0 < MAXC; r0 += CH) {
    float acc[CH];
#pragma unroll
    for (int i = 0; i < CH; i++) acc[i] = 0.f;
    for (int k = 0; k < DIM; k++) {
      float wv = ld<F32>(W, k*HIDW + t);
#pragma unroll
      for (int i = 0; i < CH; i++) {
        int m = r0 + i;
        int mc = (m < c) ? m : 0;
        float xv = ld<F32>(X, xb + mc*DIM + k);
        acc[i] += ((m < c) ? xv : 0.f) * wv;
      }
    }
    float bb = ld<F32>(Bv, t);
#pragma unroll
    for (int i = 0; i < CH; i++)
      hl[(r0+i)*HIDW + t] = f2bf(fmaxf(acc[i] + bb, 0.f));
  }
}

template<bool F32>
__device__ void stage1_l(const ushort* S, const void* W, const void* Bv,
                         ushort* hl, int t)
{
  for (int r0 = 0; r0 < MAXC; r0 += CH) {
    float acc[CH];
#pragma unroll
    for (int i = 0; i < CH; i++) acc[i] = 0.f;
    for (int k = 0; k < ATTW; k++) {
      float wv = ld<F32>(W, k*HIDW + t);
#pragma unroll
      for (int i = 0; i < CH; i++)
        acc[i] += bf2f(S[(r0+i)*BUFW + k]) * wv;
    }
    float bb = ld<F32>(Bv, t);
#pragma unroll
    for (int i = 0; i < CH; i++)
      hl[(r0+i)*HIDW + t] = f2bf(fmaxf(acc[i] + bb, 0.f));
  }
}

template<bool F32>
__device__ void stage2(const void* W, const void* Bv, const ushort* hlp,
                       ushort* dst, int t)
{
  const int col = t & (ATTW-1);
  const int h = t >> 7;
  float bb = ld<F32>(Bv, col);
  for (int m = h; m < MAXC; m += 2) {
    float a = 0.f;
    for (int k = 0; k < HIDW; k++)
      a += bf2f(hlp[m*HIDW + k]) * ld<F32>(W, k*ATTW + col);
    dst[m*BUFW + col] = f2bf(a + bb);
  }
}

template<bool F32, bool MF>
__device__ void body(const P27& P, int b, int t,
                     ushort* hl, ushort* buf0, ushort* buf1, float* sb,
                     float* q2h, float* q2, float* logit, float* selh,
                     int offset, int c, const ushort* wt)
{
  const int xb = offset * DIM;

  if (MF) stage1_mfma<F32,false>(P.nodeH, xb, c, wt + O_WK1T, P.bk1, hl, HIDW, t, MAXC);
  else    stage1_g<F32>(P.nodeH, xb, c, P.wk1, P.bk1, hl, t);
  __syncthreads();
  stage2<F32>(P.wk2, P.bk2, hl, buf0, t);
  __syncthreads();
  if (MF) stage1_mfma<F32,false>(P.nodeH, xb, c, wt + O_WQ1T, P.bq1, hl, HIDW, t, MAXC);
  else    stage1_g<F32>(P.nodeH, xb, c, P.wq1, P.bq1, hl, t);
  __syncthreads();
  stage2<F32>(P.wq2, P.bq2, hl, buf1, t);
  __syncthreads();

  for (int idx = t; idx < MAXC*MAXC; idx += BLK) {
    int m = idx / MAXC, n = idx - m*MAXC;
    float s;
    if (m < c && n < c) {
      s = 0.f;
      for (int k = 0; k < ATTW; k++)
        s += bf2f(buf0[m*BUFW + k]) * bf2f(buf1[n*BUFW + k]);
    } else s = -1e9f;
    sb[m*SB_W + n] = s * SCL;
  }
  __syncthreads();
  if (t < MAXC) {
    float* row = sb + t*SB_W;
    float mx = row[0];
    for (int n = 1; n < MAXC; n++) mx = fmaxf(mx, row[n]);
    float sum = 0.f;
    for (int n = 0; n < MAXC; n++) { float e = expf(row[n] - mx); row[n] = e; sum += e; }
    float inv = 1.f / sum;
    for (int n = 0; n < MAXC; n++) row[n] *= inv;
  }
  __syncthreads();

  if (MF) stage1_mfma<F32,false>(P.nodeH, xb, c, wt + O_WV1T, P.bv1, hl, HIDW, t, MAXC);
  else    stage1_g<F32>(P.nodeH, xb, c, P.wv1, P.bv1, hl, t);
  __syncthreads();
  stage2<F32>(P.wv2, P.bv2, hl, buf0, t);
  __syncthreads();

  {
    const int col = t & (ATTW-1);
    const int h = t >> 7;
    for (int m = h; m < MAXC; m += 2) {
      float a = 0.f;
      for (int n = 0; n < MAXC; n++)
        a += sb[m*SB_W + n] * bf2f(buf0[n*BUFW + col]);
      buf1[m*BUFW + col] = f2bf(a);
    }
  }
  __syncthreads();

  stage1_l<F32>(buf1, P.uk1, P.ubk1, hl, t);
  __syncthreads();
  stage2<F32>(P.uk2, P.ubk2, hl, buf0, t);
  __syncthreads();

  {
    float a = 0.f;
    for (int k = 0; k < DIM; k++)
      a += ld<F32>(P.molA, b*DIM + k) * ld<F32>(P.uq1, k*HIDW + t);
    q2h[t] = fmaxf(a + ld<F32>(P.ubq1, t), 0.f);
  }
  __syncthreads();
  if (t < ATTW) {
    float a = 0.f;
    for (int k = 0; k < HIDW; k++)
      a += q2h[k] * ld<F32>(P.uq2, k*ATTW + t);
    q2[t] = a + ld<F32>(P.ubq2, t);
  }
  __syncthreads();
  if (t < MAXC) {
    float s = 0.f;
    for (int k = 0; k < ATTW; k++)
      s += bf2f(buf0[t*BUFW + k]) * q2[k];
    logit[t] = s * SCL;
  }
  __syncthreads();
  if (t < ATTW) {
    float a = 0.f;
    for (int k = 0; k < MAXC; k++)
      a += logit[k] * ld<F32>(P.cs1, k*ATTW + t);
    selh[t] = fmaxf(a + ld<F32>(P.bcs1, t), 0.f);
  }
  __syncthreads();
  if (t < c) {
    float a = 0.f;
    for (int k = 0; k < ATTW; k++)
      a += selh[k] * ld<F32>(P.cs2, k*MAXC + t);
    a += ld<F32>(P.bcs2, t);
    float v = 1.f / (1.f + expf(-a));
    if (F32) ((float*)P.out)[offset + t] = v;
    else     ((ushort*)P.out)[offset + t] = f2bf(v);
  }
}

__global__ void fused_mfma(P27 P, const int* __restrict__ wsInt, const ushort* __restrict__ wt)
{
  __shared__ __align__(16) ushort hl  [MAXC*HIDW];
  __shared__ __align__(16) ushort buf0[MAXC*BUFW];
  __shared__ __align__(16) ushort buf1[MAXC*BUFW];
  __shared__ __align__(16) float  sb  [MAXC*SB_W];
  __shared__ __align__(16) float  q2h [HIDW];
  __shared__ __align__(16) float  q2  [ATTW];
  __shared__ __align__(16) float  logit[64];
  __shared__ __align__(16) float  selh[ATTW];
  const int t = threadIdx.x, b = blockIdx.x;
  const int f32m = wsInt[0];
  const int offset = wsInt[4 + b];
  const int c = P.counts[b];
  if (f32m) body<true , true>(P, b, t, hl, buf0, buf1, sb, q2h, q2, logit, selh, offset, c, wt);
  else      body<false, true>(P, b, t, hl, buf0, buf1, sb, q2h, q2, logit, selh, offset, c, wt);
}

__global__ void fused_scalar(P27 P, const int* __restrict__ wsInt)
{
  __shared__ __align__(16) ushort hl  [MAXC*HIDW];
  __shared__ __align__(16) ushort buf0[MAXC*BUFW];
  __shared__ __align__(16) ushort buf1[MAXC*BUFW];
  __shared__ __align__(16) float  sb  [MAXC*SB_W];
  __shared__ __align__(16) float  q2h [HIDW];
  __shared__ __align__(16) float  q2  [ATTW];
  __shared__ __align__(16) float  logit[64];
  __shared__ __align__(16) float  selh[ATTW];
  const int t = threadIdx.x, b = blockIdx.x;
  const int f32m = wsInt[0];
  const int offset = wsInt[4 + b];
  const int c = P.counts[b];
  if (f32m) body<true , false>(P, b, t, hl, buf0, buf1, sb, q2h, q2, logit, selh, offset, c, nullptr);
  else      body<false, false>(P, b, t, hl, buf0, buf1, sb, q2h, q2, logit, selh, offset, c, nullptr);
}

extern "C" void kernel_launch(void* const* d_in, const int* in_sizes, int n_in,
                              void* d_out, int out_size, void* d_ws, size_t ws_size,
                              hipStream_t stream) {
  P27 P;
  P.molA  = d_in[0];
  P.nodeH = d_in[1];
  P.counts= (const int*)d_in[2];
  P.wq1 = d_in[3];  P.bq1 = d_in[4];  P.wq2 = d_in[5];  P.bq2 = d_in[6];
  P.wk1 = d_in[7];  P.bk1 = d_in[8];  P.wk2 = d_in[9];  P.bk2 = d_in[10];
  P.wv1 = d_in[11]; P.bv1 = d_in[12]; P.wv2 = d_in[13]; P.bv2 = d_in[14];
  P.uk1 = d_in[15]; P.ubk1= d_in[16]; P.uk2 = d_in[17]; P.ubk2= d_in[18];
  P.uq1 = d_in[19]; P.ubq1= d_in[20]; P.uq2 = d_in[21]; P.ubq2= d_in[22];
  P.cs1 = d_in[23]; P.bcs1= d_in[24]; P.cs2 = d_in[25]; P.bcs2= d_in[26];
  P.out = d_out;
  const int nb = in_sizes[2];
  int* wsInt = (int*)d_ws;

  const long xelems = (long)in_sizes[1];          // nodeH element count (N*512)
  const long Nrows  = xelems / DIM;
  const int  ntX = (int)((Nrows + PXR - 1) / PXR);
  const int  ntA = (nb + PXR - 1) / PXR;

  size_t q2_off  = (size_t)Q2_BYTE_OFF;
  size_t kqv_off = (q2_off + (size_t)nb * ATTW * 4 + 255) & ~(size_t)255;
  const size_t need_new = kqv_off + (size_t)3 * Nrows * ATTW * 2;
  const size_t need2    = (size_t)WT_BYTE_OFF + (size_t)WT_T2ELEMS * 2;

  if (ws_size >= need_new) {
    ushort* wt   = (ushort*)((char*)d_ws + WT_BYTE_OFF);
    float*  q2ws = (float*)((char*)d_ws + q2_off);
    ushort* kqv  = (ushort*)((char*)d_ws + kqv_off);
    unsigned long long cap = (ws_size - WT_BYTE_OFF) / 2;
    const unsigned nwt = (WT2_ELEMS + BLK - 1)/BLK;
    prep2_kernel<<<dim3(nwt + 1), dim3(BLK), 0, stream>>>(P, (const int*)d_in[2], nb,
                                                          wsInt, wt, cap, nwt);
    proj_kernel<<<dim3(ntX + ntA), dim3(BLK), 0, stream>>>(P, wsInt, wt, kqv, q2ws,
                                                           Nrows, nb, ntX);
    attn_kernel<<<dim3(nb), dim3(BLK), 0, stream>>>(P, wsInt, wt, kqv, q2ws, Nrows);
  } else if (ws_size >= need2) {
    ushort* wt = (ushort*)((char*)d_ws + WT_BYTE_OFF);
    unsigned long long cap = (ws_size - WT_BYTE_OFF) / 2;
    const unsigned nwt = (WT2_ELEMS + BLK - 1)/BLK;
    prep2_kernel<<<dim3(nwt + 1), dim3(BLK), 0, stream>>>(P, (const int*)d_in[2], nb,
                                                          wsInt, wt, cap, nwt);
    fused_mfma<<<dim3(nb), dim3(BLK), 0, stream>>>(P, wsInt, wt);
  } else {
    prep_kernel<<<dim3(1), dim3(BLK), 0, stream>>>((const ushort*)d_in[0],
                                                   (const int*)d_in[2], nb, wsInt);
    fused_scalar<<<dim3(nb), dim3(BLK), 0, stream>>>(P, wsInt);
  }
}

// Round 10
// 402.577 us; speedup vs baseline: 1.1110x; 1.1110x over previous
//
#include <hip/hip_runtime.h>
#include <hip/hip_bf16.h>
#include <math.h>

#define DIM   512
#define HIDW  256
#define ATTW  128
#define MAXC  50
#define BLK   256
#define KW    128    // kb (corr/K2) stride, swizzled
#define HLW   128    // hl stride, swizzled
#define HL2   264    // fallback hidden stride
#define BUFW  136    // fallback stride
#define SB_W  52
#define CH    10
#define PXR   32     // proj row-tile
#define SCL   0.08838834764831845f  // 1/sqrt(128)

// 16B-block-preserving XOR swizzle (T2)
#define SWZ(row, e) ((e) ^ (((row) & 7) << 3))

// attn LDS layout (32000 B -> 5 blocks/CU):
#define AT_PA 12800
#define AT_KB 19200
#define AT_SM 32000

typedef float f32x4 __attribute__((ext_vector_type(4)));
typedef short s16x8 __attribute__((ext_vector_type(8)));

__device__ __forceinline__ float bf2f(ushort u){ union{unsigned i;float f;}v; v.i=((unsigned)u)<<16; return v.f; }
__device__ __forceinline__ ushort f2bf(float f){
  union{float f;unsigned i;}v; v.f=f;
  unsigned r = v.i + 0x7fffu + ((v.i>>16)&1u);
  return (ushort)(r>>16);
}
__device__ __forceinline__ s16x8 ldfrag(const ushort* p){ s16x8 v; __builtin_memcpy(&v, p, 16); return v; }
__device__ __forceinline__ f32x4 mfma16(s16x8 a, s16x8 b, f32x4 c){
  return __builtin_amdgcn_mfma_f32_16x16x32_bf16(a, b, c, 0, 0, 0);
}
// fragment-ordered weight pointer: tile (ntile,ktile) of an (N x K) matrix, lane L
__device__ __forceinline__ const ushort* fragp(const ushort* Wf, int ntile, int ktile, int KT, int L){
  return Wf + (((size_t)ntile*KT + ktile)*64 + L)*8;
}

template<bool F32>
__device__ __forceinline__ float ld(const void* p, int i){
  if (F32) return ((const float*)p)[i];
  return bf2f(((const ushort*)p)[i]);
}

struct P27 {
  const void *molA, *nodeH; const int* counts;
  const void *wq1,*bq1,*wq2,*bq2, *wk1,*bk1,*wk2,*bk2, *wv1,*bv1,*wv2,*bv2;
  const void *uk1,*ubk1,*uk2,*ubk2, *uq1,*ubq1,*uq2,*ubq2;
  const void *cs1,*bcs1,*cs2,*bcs2;
  void* out;
};

// workspace: wsInt[0]=f32flag, wsInt[4..4+nb) offsets; wt (bf16, FRAGMENT layout) at 8704
#define O_WK1T 0
#define O_WQ1T 131072
#define O_WV1T 262144
#define O_WK2T 393216
#define O_WQ2T 425984
#define O_WV2T 458752
#define O_UK1T 491520
#define O_UK2T 524288
#define WT_ELEMS   557056
#define O_UQ1TT 557056
#define O_UQ2TT 688128
#define WT2_ELEMS  720896
#define WT_T2ELEMS 393216
#define WT_BYTE_OFF 8704
#define Q2_BYTE_OFF (WT_BYTE_OFF + WT2_ELEMS*2)   // 1450496, 16B-aligned

// ---------- dtype self-detect (block-local, molA exponent histogram) ----------
__device__ __forceinline__ int detect_f32m(const ushort* molAu, int t, int* cntSh)
{
  if (t == 0) *cntSh = 0;
  __syncthreads();
  int e = (molAu[t] >> 7) & 0xFF;
  if (e >= 100 && e <= 140) atomicAdd(cntSh, 1);
  __syncthreads();
  return (*cntSh >= 220) ? 0 : 1;
}

// ---------- prep: dtype detect + exclusive scan (standalone, scalar tier) ----------
__global__ void prep_kernel(const ushort* __restrict__ molAu,
                            const int* __restrict__ counts, int nb,
                            int* __restrict__ wsInt)
{
  __shared__ int part[BLK];
  __shared__ int cnt;
  const int t = threadIdx.x;
  if (t == 0) cnt = 0;
  __syncthreads();
  int e = (molAu[t] >> 7) & 0xFF;
  if (e >= 100 && e <= 140) atomicAdd(&cnt, 1);
  const int per = (nb + BLK - 1) / BLK;
  int s = 0;
  for (int i = 0; i < per; i++) { int idx = t*per + i; if (idx < nb) s += counts[idx]; }
  part[t] = s;
  __syncthreads();
  if (t == 0) {
    int run = 0;
    for (int i = 0; i < BLK; i++) { int v = part[i]; part[i] = run; run += v; }
    wsInt[0] = (cnt >= 220) ? 0 : 1;        // 0 = bf16 inputs, 1 = f32 inputs
  }
  __syncthreads();
  int run = part[t];
  for (int i = 0; i < per; i++) {
    int idx = t*per + i;
    if (idx < nb) { wsInt[4 + idx] = run; run += counts[idx]; }
  }
}

// ---------- merged prep2: weight transpose (self-detect) + prep block ----------
__global__ void prep2_kernel(P27 P, const int* __restrict__ counts, int nb,
                             int* __restrict__ wsInt,
                             ushort* __restrict__ wt, unsigned long long cap_elems,
                             unsigned nwt)
{
  __shared__ int shInt[BLK];
  const int t = threadIdx.x;
  const unsigned bid = blockIdx.x;

  if (bid == nwt) {
    // ---- prep block: dtype detect + exclusive scan ----
    __shared__ int cnt;
    if (t == 0) cnt = 0;
    __syncthreads();
    int e = (((const ushort*)P.molA)[t] >> 7) & 0xFF;
    if (e >= 100 && e <= 140) atomicAdd(&cnt, 1);
    const int per = (nb + BLK - 1) / BLK;
    int s = 0;
    for (int i = 0; i < per; i++) { int idx = t*per + i; if (idx < nb) s += counts[idx]; }
    shInt[t] = s;
    __syncthreads();
    if (t == 0) {
      int run = 0;
      for (int i = 0; i < BLK; i++) { int v = shInt[i]; shInt[i] = run; run += v; }
      wsInt[0] = (cnt >= 220) ? 0 : 1;
    }
    __syncthreads();
    int run = shInt[t];
    for (int i = 0; i < per; i++) {
      int idx = t*per + i;
      if (idx < nb) { wsInt[4 + idx] = run; run += counts[idx]; }
    }
    return;
  }

  // ---- transpose block: self-detect dtype, then fragment-layout convert ----
  const int f32m = detect_f32m((const ushort*)P.molA, t, &shInt[0]);
  unsigned i = bid*BLK + t;
  if (i >= WT2_ELEMS) return;
  if ((unsigned long long)i >= cap_elems) return;
  const void* src; unsigned j; int K, ldw;
  if (i < O_WK2T) {                 // w1-type: N=256, K=512, src[k*256+n]
    int m = i / 131072; j = i - m*131072;
    src = (m==0) ? P.wk1 : ((m==1) ? P.wq1 : P.wv1);
    K = 512; ldw = HIDW;
  } else if (i < O_UK1T) {          // w2-type: N=128, K=256, src[k*128+n]
    int m = (i - O_WK2T) / 32768; j = (i - O_WK2T) - m*32768;
    src = (m==0) ? P.wk2 : ((m==1) ? P.wq2 : P.wv2);
    K = 256; ldw = ATTW;
  } else if (i < O_UK2T) {          // uk1: N=256, K=128
    j = i - O_UK1T; src = P.uk1;  K = 128; ldw = HIDW;
  } else if (i < O_UQ1TT) {         // uk2: N=128, K=256
    j = i - O_UK2T; src = P.uk2;  K = 256; ldw = ATTW;
  } else if (i < O_UQ2TT) {         // uq1: N=256, K=512
    j = i - O_UQ1TT; src = P.uq1; K = 512; ldw = HIDW;
  } else {                          // uq2: N=128, K=256
    j = i - O_UQ2TT; src = P.uq2; K = 256; ldw = ATTW;
  }
  int tile = j >> 9, within = j & 511;
  int Lp = within >> 3, jj = within & 7;
  int l16 = Lp & 15, quad = Lp >> 4;
  int KT = K >> 5;
  int ntile = tile / KT, ktile = tile - ntile*KT;
  int n = ntile*16 + l16;
  int k = ktile*32 + quad*8 + jj;
  int idx = k*ldw + n;
  float v = f32m ? ((const float*)src)[idx] : bf2f(((const ushort*)src)[idx]);
  wt[i] = f2bf(v);
}

// ================= fused projection GEMM (r4-exact, measured 151 µs) =================
__global__ void __launch_bounds__(BLK, 3)
proj_kernel(P27 P, const int* __restrict__ wsInt, const ushort* __restrict__ wt,
            ushort* __restrict__ kqv, float* __restrict__ q2ws,
            long Nrows, int nb, int ntX)
{
  __shared__ __align__(16) ushort xs [PXR*DIM];    // 32768 B, swizzled
  __shared__ __align__(16) ushort hid[PXR*HIDW];   // 16384 B, swizzled
  const int t = threadIdx.x, bid = blockIdx.x;
  const int f32m = wsInt[0];
  const long NP = Nrows * ATTW;
  const bool isml = (bid >= ntX);
  const long r0 = isml ? (long)(bid - ntX)*PXR : (long)bid*PXR;
  int rows;
  const void* X;
  if (isml) { int rem = nb - (int)r0;        rows = (rem < PXR) ? rem : PXR; X = P.molA; }
  else      { long rem = Nrows - r0;         rows = (rem < PXR) ? (int)rem : PXR; X = P.nodeH; }
  if (rows <= 0) return;

  // ---- stage X-tile -> xs (bf16, swizzled; conversion paid once) ----
  for (int i = t*8; i < PXR*DIM; i += BLK*8) {
    int row = i >> 9;
    int e   = i & (DIM-1);
    s16x8 o = {};
    if (row < rows) {
      if (f32m) {
        const float* xp = (const float*)X + (r0 + row)*DIM + e;
        f32x4 v0, v1; __builtin_memcpy(&v0, xp, 16); __builtin_memcpy(&v1, xp+4, 16);
#pragma unroll
        for (int q = 0; q < 4; q++) { o[q] = (short)f2bf(v0[q]); o[4+q] = (short)f2bf(v1[q]); }
      } else {
        o = ldfrag((const ushort*)X + (r0 + row)*DIM + e);
      }
    }
    __builtin_memcpy(&xs[row*DIM + SWZ(row, e)], &o, 16);
  }
  __syncthreads();

  const int w = t >> 6, L = t & 63, quad = L >> 4, l16 = L & 15;
  const int nsets = isml ? 1 : 3;
  for (int si = 0; si < nsets; si++) {
    const ushort *W1t, *W2t; const void *b1, *b2;
    if (isml)        { W1t = wt+O_UQ1TT; b1 = P.ubq1; W2t = wt+O_UQ2TT; b2 = P.ubq2; }
    else if (si==0)  { W1t = wt+O_WK1T;  b1 = P.bk1;  W2t = wt+O_WK2T;  b2 = P.bk2;  }
    else if (si==1)  { W1t = wt+O_WQ1T;  b1 = P.bq1;  W2t = wt+O_WQ2T;  b2 = P.bq2;  }
    else             { W1t = wt+O_WV1T;  b1 = P.bv1;  W2t = wt+O_WV2T;  b2 = P.bv2;  }

    // ---- layer1: xs(32x512) @ W1t -> acc; wave w owns cols [w*64, w*64+64) ----
    f32x4 acc[2][4];
#pragma unroll
    for (int i = 0; i < 2; i++)
#pragma unroll
      for (int jn = 0; jn < 4; jn++) acc[i][jn] = (f32x4){0.f,0.f,0.f,0.f};
#pragma unroll 2
    for (int k0 = 0; k0 < DIM; k0 += 32) {
      const int kt = k0 >> 5;
      const int eo = SWZ(l16, k0 + quad*8);
      s16x8 a0 = ldfrag(xs + l16*DIM + eo);
      s16x8 a1 = ldfrag(xs + (16 + l16)*DIM + eo);
#pragma unroll
      for (int nt = 0; nt < 4; nt++) {
        s16x8 b = ldfrag(fragp(W1t, w*4 + nt, kt, 16, L));
        acc[0][nt] = mfma16(a0, b, acc[0][nt]);
        acc[1][nt] = mfma16(a1, b, acc[1][nt]);
      }
    }
    __syncthreads();   // prior set's layer2 hid reads complete
#pragma unroll
    for (int nt = 0; nt < 4; nt++) {
      int col = w*64 + nt*16 + l16;
      float bb = f32m ? ((const float*)b1)[col] : bf2f(((const ushort*)b1)[col]);
#pragma unroll
      for (int mt = 0; mt < 2; mt++)
#pragma unroll
        for (int r = 0; r < 4; r++) {
          int row = mt*16 + quad*4 + r;
          hid[row*HIDW + SWZ(row, col)] = f2bf(fmaxf(acc[mt][nt][r] + bb, 0.f));
        }
    }
    __syncthreads();

    // ---- layer2: hid(32x256) @ W2t -> out; wave w owns cols [w*32, w*32+32) ----
    f32x4 acc2[2][2];
#pragma unroll
    for (int i = 0; i < 2; i++) { acc2[i][0] = (f32x4){0.f,0.f,0.f,0.f}; acc2[i][1] = (f32x4){0.f,0.f,0.f,0.f}; }
#pragma unroll 2
    for (int k0 = 0; k0 < HIDW; k0 += 32) {
      const int kt = k0 >> 5;
      const int eo = SWZ(l16, k0 + quad*8);
      s16x8 a0 = ldfrag(hid + l16*HIDW + eo);
      s16x8 a1 = ldfrag(hid + (16 + l16)*HIDW + eo);
      s16x8 b0 = ldfrag(fragp(W2t, w*2,     kt, 8, L));
      s16x8 b1v= ldfrag(fragp(W2t, w*2 + 1, kt, 8, L));
      acc2[0][0] = mfma16(a0, b0,  acc2[0][0]);
      acc2[0][1] = mfma16(a0, b1v, acc2[0][1]);
      acc2[1][0] = mfma16(a1, b0,  acc2[1][0]);
      acc2[1][1] = mfma16(a1, b1v, acc2[1][1]);
    }
#pragma unroll
    for (int nt = 0; nt < 2; nt++) {
      int col = w*32 + nt*16 + l16;
      float bb = f32m ? ((const float*)b2)[col] : bf2f(((const ushort*)b2)[col]);
#pragma unroll
      for (int mt = 0; mt < 2; mt++)
#pragma unroll
        for (int r = 0; r < 4; r++) {
          int row = mt*16 + quad*4 + r;
          if (row < rows) {
            float v = acc2[mt][nt][r] + bb;
            if (isml) q2ws[(r0 + row)*ATTW + col] = v;
            else      kqv[(size_t)si*NP + (r0 + row)*ATTW + col] = f2bf(v);
          }
        }
    }
  }
}

// ================= per-molecule attention kernel (r6 structure + setprio) =================

__device__ __forceinline__ void scores_g(const ushort* __restrict__ Kp,
                                         const ushort* __restrict__ Qp,
                                         long offset, int c,
                                         float* __restrict__ sb, int t)
{
  const int w = t >> 6, L = t & 63, quad = L >> 4, l16 = L & 15;
  f32x4 acc[4];
#pragma unroll
  for (int i = 0; i < 4; i++) acc[i] = (f32x4){0.f,0.f,0.f,0.f};
  const int col = w*16 + l16;
  const long gq = offset + ((col < c) ? col : 0);
  long ga[4];
#pragma unroll
  for (int mt = 0; mt < 4; mt++) {
    int row = mt*16 + l16;
    ga[mt] = offset + ((row < c) ? row : 0);
  }
  __builtin_amdgcn_s_setprio(1);
#pragma unroll
  for (int k0 = 0; k0 < ATTW; k0 += 32) {
    s16x8 b = ldfrag(Qp + (size_t)gq*ATTW + k0 + quad*8);
#pragma unroll
    for (int mt = 0; mt < 4; mt++) {
      s16x8 a = ldfrag(Kp + (size_t)ga[mt]*ATTW + k0 + quad*8);
      acc[mt] = mfma16(a, b, acc[mt]);
    }
  }
  __builtin_amdgcn_s_setprio(0);
#pragma unroll
  for (int mt = 0; mt < 4; mt++)
#pragma unroll
    for (int r = 0; r < 4; r++) {
      int row = mt*16 + quad*4 + r;
      if (row < MAXC && col < MAXC)
        sb[row*SB_W + col] = (row < c && col < c) ? acc[mt][r]*SCL : -1e9f*SCL;
    }
}

__device__ __forceinline__ void softmax_pa(float* __restrict__ sb,
                                           ushort* __restrict__ pa, int c, int t)
{
  const int m = t >> 2, j = t & 3;
  if (m < MAXC) {
    float* row = sb + m*SB_W;
    float mx = -3.4e38f;
    for (int n = j; n < MAXC; n += 4) mx = fmaxf(mx, row[n]);
    mx = fmaxf(mx, __shfl_xor(mx, 1));
    mx = fmaxf(mx, __shfl_xor(mx, 2));
    float sum = 0.f;
    for (int n = j; n < MAXC; n += 4) { float e = expf(row[n] - mx); row[n] = e; sum += e; }
    sum += __shfl_xor(sum, 1);
    sum += __shfl_xor(sum, 2);
    float inv = 1.f / sum;
    for (int n = j; n < 64; n += 4)
      pa[m*64 + SWZ(m, n)] = (n < MAXC) ? f2bf(row[n] * inv) : (ushort)0;
  }
}

__device__ __forceinline__ void corr_half(const ushort* __restrict__ pa,
                                          const ushort* __restrict__ vt,
                                          ushort* __restrict__ dst, int colbase, int t)
{
  const int w = t >> 6, L = t & 63, quad = L >> 4, l16 = L & 15;
  f32x4 acc[4];
#pragma unroll
  for (int i = 0; i < 4; i++) acc[i] = (f32x4){0.f,0.f,0.f,0.f};
  const int dr = w*16 + l16;
  __builtin_amdgcn_s_setprio(1);
#pragma unroll
  for (int k0 = 0; k0 < 64; k0 += 32) {
    s16x8 b = ldfrag(vt + dr*64 + SWZ(dr, k0 + quad*8));
#pragma unroll
    for (int mt = 0; mt < 4; mt++) {
      int row = mt*16 + l16;
      int ar = (row < MAXC) ? row : 0;
      s16x8 a = ldfrag(pa + ar*64 + SWZ(ar, k0 + quad*8));
      acc[mt] = mfma16(a, b, acc[mt]);
    }
  }
  __builtin_amdgcn_s_setprio(0);
  const int col = colbase + w*16 + l16;
#pragma unroll
  for (int mt = 0; mt < 4; mt++)
#pragma unroll
    for (int r = 0; r < 4; r++) {
      int row = mt*16 + quad*4 + r;
      if (row < MAXC)
        dst[row*KW + SWZ(row, col)] = f2bf(acc[mt][r]);
    }
}

// K2-stage1 half (uk1: N=256,K=128 frag layout)
template<bool F32>
__device__ __forceinline__ void s1l_half(const ushort* __restrict__ src,
                                         const ushort* __restrict__ W1t,
                                         const void* __restrict__ Bv,
                                         ushort* __restrict__ hl, int t, int h)
{
  const int w = t >> 6, L = t & 63, quad = L >> 4, l16 = L & 15;
  f32x4 acc[4][2];
#pragma unroll
  for (int i = 0; i < 4; i++) { acc[i][0] = (f32x4){0.f,0.f,0.f,0.f}; acc[i][1] = (f32x4){0.f,0.f,0.f,0.f}; }
  __builtin_amdgcn_s_setprio(1);
#pragma unroll
  for (int k0 = 0; k0 < ATTW; k0 += 32) {
    const int kt = k0 >> 5;
    s16x8 b0 = ldfrag(fragp(W1t, h*8 + w*2,     kt, 4, L));
    s16x8 b1 = ldfrag(fragp(W1t, h*8 + w*2 + 1, kt, 4, L));
#pragma unroll
    for (int mt = 0; mt < 4; mt++) {
      int row = mt*16 + l16;
      int ar = (row < MAXC) ? row : 0;
      s16x8 a = ldfrag(src + ar*KW + SWZ(ar, k0 + quad*8));
      acc[mt][0] = mfma16(a, b0, acc[mt][0]);
      acc[mt][1] = mfma16(a, b1, acc[mt][1]);
    }
  }
  __builtin_amdgcn_s_setprio(0);
#pragma unroll
  for (int nt = 0; nt < 2; nt++) {
    int lcol = w*32 + nt*16 + l16;
    float bb = ld<F32>(Bv, h*128 + lcol);
#pragma unroll
    for (int mt = 0; mt < 4; mt++)
#pragma unroll
      for (int r = 0; r < 4; r++) {
        int row = mt*16 + quad*4 + r;
        if (row < MAXC)
          hl[row*HLW + SWZ(row, lcol)] = f2bf(fmaxf(acc[mt][nt][r] + bb, 0.f));
      }
  }
}

// K2-stage2 partial (uk2: N=128,K=256 frag layout), hidden half h
template<bool F32>
__device__ __forceinline__ void s2_partial(const ushort* __restrict__ hl,
                                           const ushort* __restrict__ W2t,
                                           int h, f32x4 (&acc)[4][2], int t)
{
  const int w = t >> 6, L = t & 63, quad = L >> 4, l16 = L & 15;
  __builtin_amdgcn_s_setprio(1);
#pragma unroll
  for (int k0 = 0; k0 < 128; k0 += 32) {
    const int kt = h*4 + (k0 >> 5);
    s16x8 b0 = ldfrag(fragp(W2t, w*2,     kt, 8, L));
    s16x8 b1 = ldfrag(fragp(W2t, w*2 + 1, kt, 8, L));
#pragma unroll
    for (int mt = 0; mt < 4; mt++) {
      int row = mt*16 + l16;
      int ar = (row < MAXC) ? row : 0;
      s16x8 a = ldfrag(hl + ar*HLW + SWZ(ar, k0 + quad*8));
      acc[mt][0] = mfma16(a, b0, acc[mt][0]);
      acc[mt][1] = mfma16(a, b1, acc[mt][1]);
    }
  }
  __builtin_amdgcn_s_setprio(0);
}

template<bool F32>
__device__ __forceinline__ void s2_store(f32x4 (&acc)[4][2], const void* __restrict__ Bv,
                                         ushort* __restrict__ dst, int t)
{
  const int w = t >> 6, L = t & 63, quad = L >> 4, l16 = L & 15;
#pragma unroll
  for (int nt = 0; nt < 2; nt++) {
    int col = w*32 + nt*16 + l16;
    float bb = ld<F32>(Bv, col);
#pragma unroll
    for (int mt = 0; mt < 4; mt++)
#pragma unroll
      for (int r = 0; r < 4; r++) {
        int row = mt*16 + quad*4 + r;
        if (row < MAXC)
          dst[row*KW + SWZ(row, col)] = f2bf(acc[mt][nt][r] + bb);
      }
  }
}

template<bool F32>
__device__ void attn_body(const P27& P, int b, int t, char* smem,
                          long offset, int c,
                          const ushort* __restrict__ wt,
                          const ushort* __restrict__ Kp, const ushort* __restrict__ Qp,
                          const ushort* __restrict__ Vp, const float* __restrict__ q2ws)
{
  float*  sb = (float*)smem;
  ushort* vt = (ushort*)smem;
  ushort* hl = (ushort*)smem;
  ushort* pa = (ushort*)(smem + AT_PA);
  ushort* kb = (ushort*)(smem + AT_KB);
  float* q2   = (float*)smem;
  float* lgt  = (float*)(smem + 512);
  float* selh = (float*)(smem + 768);

  scores_g(Kp, Qp, offset, c, sb, t);
  __syncthreads();
  softmax_pa(sb, pa, c, t);
  __syncthreads();

#pragma unroll
  for (int half = 0; half < 2; half++) {
    for (int i = t; i < 512; i += BLK) {
      int atom = i & 63, chunk = i >> 6;
      s16x8 f = {};
      if (atom < c) f = ldfrag(Vp + (size_t)(offset + atom)*ATTW + half*64 + chunk*8);
#pragma unroll
      for (int j = 0; j < 8; j++) {
        int d = chunk*8 + j;
        vt[d*64 + SWZ(d, atom)] = (ushort)f[j];
      }
    }
    __syncthreads();
    corr_half(pa, vt, kb, half*64, t);
    __syncthreads();
  }

  {
    f32x4 acc[4][2];
#pragma unroll
    for (int i = 0; i < 4; i++) { acc[i][0] = (f32x4){0.f,0.f,0.f,0.f}; acc[i][1] = (f32x4){0.f,0.f,0.f,0.f}; }
    s1l_half<F32>(kb, wt + O_UK1T, P.ubk1, hl, t, 0); __syncthreads();
    s2_partial<F32>(hl, wt + O_UK2T, 0, acc, t);      __syncthreads();
    s1l_half<F32>(kb, wt + O_UK1T, P.ubk1, hl, t, 1); __syncthreads();
    s2_partial<F32>(hl, wt + O_UK2T, 1, acc, t);
    s2_store<F32>(acc, P.ubk2, kb, t);
    __syncthreads();
  }

  if (t < ATTW) q2[t] = q2ws[(size_t)b*ATTW + t];
  __syncthreads();
  if (t < MAXC) {
    float s = 0.f;
    for (int k = 0; k < ATTW; k++)
      s += bf2f(kb[t*KW + SWZ(t, k)]) * q2[k];
    lgt[t] = s * SCL;
  }
  __syncthreads();
  if (t < ATTW) {
    float a = 0.f;
    for (int k = 0; k < MAXC; k++)
      a += lgt[k] * ld<F32>(P.cs1, k*ATTW + t);
    selh[t] = fmaxf(a + ld<F32>(P.bcs1, t), 0.f);
  }
  __syncthreads();
  if (t < c) {
    float a = 0.f;
    for (int k = 0; k < ATTW; k++)
      a += selh[k] * ld<F32>(P.cs2, k*MAXC + t);
    a += ld<F32>(P.bcs2, t);
    float v = 1.f / (1.f + expf(-a));
    if (F32) ((float*)P.out)[offset + t] = v;
    else     ((ushort*)P.out)[offset + t] = f2bf(v);
  }
}

__global__ void __launch_bounds__(BLK, 5)
attn_kernel(P27 P, const int* __restrict__ wsInt, const ushort* __restrict__ wt,
            const ushort* __restrict__ kqv, const float* __restrict__ q2ws, long Nrows)
{
  __shared__ __align__(16) char smem[AT_SM];
  const int t = threadIdx.x, b = blockIdx.x;
  const int f32m = wsInt[0];
  const long offset = wsInt[4 + b];
  const int c = P.counts[b];
  const long NP = Nrows * ATTW;
  const ushort* Kp = kqv;
  const ushort* Qp = kqv + NP;
  const ushort* Vp = kqv + 2*NP;
  if (f32m) attn_body<true >(P, b, t, smem, offset, c, wt, Kp, Qp, Vp, q2ws);
  else      attn_body<false>(P, b, t, smem, offset, c, wt, Kp, Qp, Vp, q2ws);
}

// ================= fallback tiers =================
template<bool F32, bool XB>
__device__ __forceinline__ void stage1_mfma(const void* __restrict__ X, int xb, int c,
                                            const ushort* __restrict__ Wt,
                                            const void* __restrict__ Bv,
                                            ushort* __restrict__ hl, int hls, int t,
                                            int wlim)
{
  const int w = t >> 6, L = t & 63, quad = L >> 4, l16 = L & 15;
  f32x4 acc[4][4];
#pragma unroll
  for (int i = 0; i < 4; i++)
#pragma unroll
    for (int j = 0; j < 4; j++) acc[i][j] = (f32x4){0.f,0.f,0.f,0.f};

  bool va[4]; int rr[4];
#pragma unroll
  for (int mt = 0; mt < 4; mt++) {
    int row = mt*16 + l16;
    va[mt] = (row < c);
    rr[mt] = va[mt] ? row : 0;
  }

#pragma unroll 2
  for (int k0 = 0; k0 < DIM; k0 += 32) {
    const int kt = k0 >> 5;
    s16x8 a[4];
#pragma unroll
    for (int mt = 0; mt < 4; mt++) {
      s16x8 z = {};
      if (va[mt]) {
        if (XB || !F32) {
          a[mt] = ldfrag((const ushort*)X + xb + rr[mt]*DIM + k0 + quad*8);
        } else {
          const float* xp = (const float*)X + xb + rr[mt]*DIM + k0 + quad*8;
          f32x4 v0, v1;
          __builtin_memcpy(&v0, xp, 16);
          __builtin_memcpy(&v1, xp+4, 16);
          s16x8 v;
#pragma unroll
          for (int j = 0; j < 4; j++) { v[j] = (short)f2bf(v0[j]); v[4+j] = (short)f2bf(v1[j]); }
          a[mt] = v;
        }
      } else a[mt] = z;
    }
#pragma unroll
    for (int nt = 0; nt < 4; nt++) {
      s16x8 b = ldfrag(fragp(Wt, w*4 + nt, kt, 16, L));
#pragma unroll
      for (int mt = 0; mt < 4; mt++)
        acc[mt][nt] = mfma16(a[mt], b, acc[mt][nt]);
    }
  }
#pragma unroll
  for (int nt = 0; nt < 4; nt++) {
    int col = w*64 + nt*16 + l16;
    float bb = ld<F32>(Bv, col);
#pragma unroll
    for (int mt = 0; mt < 4; mt++)
#pragma unroll
      for (int r = 0; r < 4; r++) {
        int row = mt*16 + quad*4 + r;
        if (row < wlim)
          hl[row*hls + col] = f2bf(fmaxf(acc[mt][nt][r] + bb, 0.f));
      }
  }
}

template<bool F32>
__device__ void stage1_g(const void* X, int xb, int c,
                         const void* W, const void* Bv, ushort* hl, int t)
{
  for (int r0 = 0; r0 < MAXC; r0 += CH) {
    float acc[CH];
#pragma unroll
    for (int i = 0; i < CH; i++) acc[i] = 0.f;
    for (int k = 0; k < DIM; k++) {
      float wv = ld<F32>(W, k*HIDW + t);
#pragma unroll
      for (int i = 0; i < CH; i++) {
        int m = r0 + i;
        int mc = (m < c) ? m : 0;
        float xv = ld<F32>(X, xb + mc*DIM + k);
        acc[i] += ((m < c) ? xv : 0.f) * wv;
      }
    }
    float bb = ld<F32>(Bv, t);
#pragma unroll
    for (int i = 0; i < CH; i++)
      hl[(r0+i)*HIDW + t] = f2bf(fmaxf(acc[i] + bb, 0.f));
  }
}

template<bool F32>
__device__ void stage1_l(const ushort* S, const void* W, const void* Bv,
                         ushort* hl, int t)
{
  for (int r0 = 0; r0 < MAXC; r0 += CH) {
    float acc[CH];
#pragma unroll
    for (int i = 0; i < CH; i++) acc[i] = 0.f;
    for (int k = 0; k < ATTW; k++) {
      float wv = ld<F32>(W, k*HIDW + t);
#pragma unroll
      for (int i = 0; i < CH; i++)
        acc[i] += bf2f(S[(r0+i)*BUFW + k]) * wv;
    }
    float bb = ld<F32>(Bv, t);
#pragma unroll
    for (int i = 0; i < CH; i++)
      hl[(r0+i)*HIDW + t] = f2bf(fmaxf(acc[i] + bb, 0.f));
  }
}

template<bool F32>
__device__ void stage2(const void* W, const void* Bv, const ushort* hlp,
                       ushort* dst, int t)
{
  const int col = t & (ATTW-1);
  const int h = t >> 7;
  float bb = ld<F32>(Bv, col);
  for (int m = h; m < MAXC; m += 2) {
    float a = 0.f;
    for (int k = 0; k < HIDW; k++)
      a += bf2f(hlp[m*HIDW + k]) * ld<F32>(W, k*ATTW + col);
    dst[m*BUFW + col] = f2bf(a + bb);
  }
}

template<bool F32, bool MF>
__device__ void body(const P27& P, int b, int t,
                     ushort* hl, ushort* buf0, ushort* buf1, float* sb,
                     float* q2h, float* q2, float* logit, float* selh,
                     int offset, int c, const ushort* wt)
{
  const int xb = offset * DIM;

  if (MF) stage1_mfma<F32,false>(P.nodeH, xb, c, wt + O_WK1T, P.bk1, hl, HIDW, t, MAXC);
  else    stage1_g<F32>(P.nodeH, xb, c, P.wk1, P.bk1, hl, t);
  __syncthreads();
  stage2<F32>(P.wk2, P.bk2, hl, buf0, t);
  __syncthreads();
  if (MF) stage1_mfma<F32,false>(P.nodeH, xb, c, wt + O_WQ1T, P.bq1, hl, HIDW, t, MAXC);
  else    stage1_g<F32>(P.nodeH, xb, c, P.wq1, P.bq1, hl, t);
  __syncthreads();
  stage2<F32>(P.wq2, P.bq2, hl, buf1, t);
  __syncthreads();

  for (int idx = t; idx < MAXC*MAXC; idx += BLK) {
    int m = idx / MAXC, n = idx - m*MAXC;
    float s;
    if (m < c && n < c) {
      s = 0.f;
      for (int k = 0; k < ATTW; k++)
        s += bf2f(buf0[m*BUFW + k]) * bf2f(buf1[n*BUFW + k]);
    } else s = -1e9f;
    sb[m*SB_W + n] = s * SCL;
  }
  __syncthreads();
  if (t < MAXC) {
    float* row = sb + t*SB_W;
    float mx = row[0];
    for (int n = 1; n < MAXC; n++) mx = fmaxf(mx, row[n]);
    float sum = 0.f;
    for (int n = 0; n < MAXC; n++) { float e = expf(row[n] - mx); row[n] = e; sum += e; }
    float inv = 1.f / sum;
    for (int n = 0; n < MAXC; n++) row[n] *= inv;
  }
  __syncthreads();

  if (MF) stage1_mfma<F32,false>(P.nodeH, xb, c, wt + O_WV1T, P.bv1, hl, HIDW, t, MAXC);
  else    stage1_g<F32>(P.nodeH, xb, c, P.wv1, P.bv1, hl, t);
  __syncthreads();
  stage2<F32>(P.wv2, P.bv2, hl, buf0, t);
  __syncthreads();

  {
    const int col = t & (ATTW-1);
    const int h = t >> 7;
    for (int m = h; m < MAXC; m += 2) {
      float a = 0.f;
      for (int n = 0; n < MAXC; n++)
        a += sb[m*SB_W + n] * bf2f(buf0[n*BUFW + col]);
      buf1[m*BUFW + col] = f2bf(a);
    }
  }
  __syncthreads();

  stage1_l<F32>(buf1, P.uk1, P.ubk1, hl, t);
  __syncthreads();
  stage2<F32>(P.uk2, P.ubk2, hl, buf0, t);
  __syncthreads();

  {
    float a = 0.f;
    for (int k = 0; k < DIM; k++)
      a += ld<F32>(P.molA, b*DIM + k) * ld<F32>(P.uq1, k*HIDW + t);
    q2h[t] = fmaxf(a + ld<F32>(P.ubq1, t), 0.f);
  }
  __syncthreads();
  if (t < ATTW) {
    float a = 0.f;
    for (int k = 0; k < HIDW; k++)
      a += q2h[k] * ld<F32>(P.uq2, k*ATTW + t);
    q2[t] = a + ld<F32>(P.ubq2, t);
  }
  __syncthreads();
  if (t < MAXC) {
    float s = 0.f;
    for (int k = 0; k < ATTW; k++)
      s += bf2f(buf0[t*BUFW + k]) * q2[k];
    logit[t] = s * SCL;
  }
  __syncthreads();
  if (t < ATTW) {
    float a = 0.f;
    for (int k = 0; k < MAXC; k++)
      a += logit[k] * ld<F32>(P.cs1, k*ATTW + t);
    selh[t] = fmaxf(a + ld<F32>(P.bcs1, t), 0.f);
  }
  __syncthreads();
  if (t < c) {
    float a = 0.f;
    for (int k = 0; k < ATTW; k++)
      a += selh[k] * ld<F32>(P.cs2, k*MAXC + t);
    a += ld<F32>(P.bcs2, t);
    float v = 1.f / (1.f + expf(-a));
    if (F32) ((float*)P.out)[offset + t] = v;
    else     ((ushort*)P.out)[offset + t] = f2bf(v);
  }
}

__global__ void fused_mfma(P27 P, const int* __restrict__ wsInt, const ushort* __restrict__ wt)
{
  __shared__ __align__(16) ushort hl  [MAXC*HIDW];
  __shared__ __align__(16) ushort buf0[MAXC*BUFW];
  __shared__ __align__(16) ushort buf1[MAXC*BUFW];
  __shared__ __align__(16) float  sb  [MAXC*SB_W];
  __shared__ __align__(16) float  q2h [HIDW];
  __shared__ __align__(16) float  q2  [ATTW];
  __shared__ __align__(16) float  logit[64];
  __shared__ __align__(16) float  selh[ATTW];
  const int t = threadIdx.x, b = blockIdx.x;
  const int f32m = wsInt[0];
  const int offset = wsInt[4 + b];
  const int c = P.counts[b];
  if (f32m) body<true , true>(P, b, t, hl, buf0, buf1, sb, q2h, q2, logit, selh, offset, c, wt);
  else      body<false, true>(P, b, t, hl, buf0, buf1, sb, q2h, q2, logit, selh, offset, c, wt);
}

__global__ void fused_scalar(P27 P, const int* __restrict__ wsInt)
{
  __shared__ __align__(16) ushort hl  [MAXC*HIDW];
  __shared__ __align__(16) ushort buf0[MAXC*BUFW];
  __shared__ __align__(16) ushort buf1[MAXC*BUFW];
  __shared__ __align__(16) float  sb  [MAXC*SB_W];
  __shared__ __align__(16) float  q2h [HIDW];
  __shared__ __align__(16) float  q2  [ATTW];
  __shared__ __align__(16) float  logit[64];
  __shared__ __align__(16) float  selh[ATTW];
  const int t = threadIdx.x, b = blockIdx.x;
  const int f32m = wsInt[0];
  const int offset = wsInt[4 + b];
  const int c = P.counts[b];
  if (f32m) body<true , false>(P, b, t, hl, buf0, buf1, sb, q2h, q2, logit, selh, offset, c, nullptr);
  else      body<false, false>(P, b, t, hl, buf0, buf1, sb, q2h, q2, logit, selh, offset, c, nullptr);
}

extern "C" void kernel_launch(void* const* d_in, const int* in_sizes, int n_in,
                              void* d_out, int out_size, void* d_ws, size_t ws_size,
                              hipStream_t stream) {
  P27 P;
  P.molA  = d_in[0];
  P.nodeH = d_in[1];
  P.counts= (const int*)d_in[2];
  P.wq1 = d_in[3];  P.bq1 = d_in[4];  P.wq2 = d_in[5];  P.bq2 = d_in[6];
  P.wk1 = d_in[7];  P.bk1 = d_in[8];  P.wk2 = d_in[9];  P.bk2 = d_in[10];
  P.wv1 = d_in[11]; P.bv1 = d_in[12]; P.wv2 = d_in[13]; P.bv2 = d_in[14];
  P.uk1 = d_in[15]; P.ubk1= d_in[16]; P.uk2 = d_in[17]; P.ubk2= d_in[18];
  P.uq1 = d_in[19]; P.ubq1= d_in[20]; P.uq2 = d_in[21]; P.ubq2= d_in[22];
  P.cs1 = d_in[23]; P.bcs1= d_in[24]; P.cs2 = d_in[25]; P.bcs2= d_in[26];
  P.out = d_out;
  const int nb = in_sizes[2];
  int* wsInt = (int*)d_ws;

  const long xelems = (long)in_sizes[1];          // nodeH element count (N*512)
  const long Nrows  = xelems / DIM;
  const int  ntX = (int)((Nrows + PXR - 1) / PXR);
  const int  ntA = (nb + PXR - 1) / PXR;

  size_t q2_off  = (size_t)Q2_BYTE_OFF;
  size_t kqv_off = (q2_off + (size_t)nb * ATTW * 4 + 255) & ~(size_t)255;
  const size_t need_new = kqv_off + (size_t)3 * Nrows * ATTW * 2;
  const size_t need2    = (size_t)WT_BYTE_OFF + (size_t)WT_T2ELEMS * 2;

  if (ws_size >= need_new) {
    ushort* wt   = (ushort*)((char*)d_ws + WT_BYTE_OFF);
    float*  q2ws = (float*)((char*)d_ws + q2_off);
    ushort* kqv  = (ushort*)((char*)d_ws + kqv_off);
    unsigned long long cap = (ws_size - WT_BYTE_OFF) / 2;
    const unsigned nwt = (WT2_ELEMS + BLK - 1)/BLK;
    prep2_kernel<<<dim3(nwt + 1), dim3(BLK), 0, stream>>>(P, (const int*)d_in[2], nb,
                                                          wsInt, wt, cap, nwt);
    proj_kernel<<<dim3(ntX + ntA), dim3(BLK), 0, stream>>>(P, wsInt, wt, kqv, q2ws,
                                                           Nrows, nb, ntX);
    attn_kernel<<<dim3(nb), dim3(BLK), 0, stream>>>(P, wsInt, wt, kqv, q2ws, Nrows);
  } else if (ws_size >= need2) {
    ushort* wt = (ushort*)((char*)d_ws + WT_BYTE_OFF);
    unsigned long long cap = (ws_size - WT_BYTE_OFF) / 2;
    const unsigned nwt = (WT2_ELEMS + BLK - 1)/BLK;
    prep2_kernel<<<dim3(nwt + 1), dim3(BLK), 0, stream>>>(P, (const int*)d_in[2], nb,
                                                          wsInt, wt, cap, nwt);
    fused_mfma<<<dim3(nb), dim3(BLK), 0, stream>>>(P, wsInt, wt);
  } else {
    prep_kernel<<<dim3(1), dim3(BLK), 0, stream>>>((const ushort*)d_in[0],
                                                   (const int*)d_in[2], nb, wsInt);
    fused_scalar<<<dim3(nb), dim3(BLK), 0, stream>>>(P, wsInt);
  }
}